// Round 1
// baseline (839.104 us; speedup 1.0000x reference)
//
#include <hip/hip_runtime.h>
#include <math.h>

#define NHEADS 12
#define HD 64
#define SEQ 2048
#define CD 768
#define BB 2
#define QKVD 2304   // 3*CD

// ---------------------------------------------------------------------------
// C[M,N] = A[M,K] @ B[N,K]^T (+bias).  A,B row-major, K-contiguous ("NT").
// 64x64 tile, BK=16, 256 threads, 4x4 microtile per thread.
// ---------------------------------------------------------------------------
template<bool BIAS>
__global__ __launch_bounds__(256)
void gemm_nt_kernel(const float* __restrict__ A, const float* __restrict__ B,
                    const float* __restrict__ bias, float* __restrict__ C,
                    int M, int N, int K) {
    __shared__ float As[16][64];   // As[k][m]; f4 reads broadcast across tx -> conflict-free
    __shared__ float Bs[16][65];   // Bs[k][n]; stride 65 -> scalar col reads 2-way (free)

    const int tid = threadIdx.x;
    const int tx  = tid & 15;
    const int ty  = tid >> 4;
    const int rowbase = blockIdx.y << 6;
    const int colbase = blockIdx.x << 6;
    const int lr = tid >> 2;          // 0..63 tile row
    const int lk = (tid & 3) << 2;    // 0,4,8,12 k-chunk

    const float* Ap = A + (size_t)(rowbase + lr) * K + lk;
    const float* Bp = B + (size_t)(colbase + lr) * K + lk;

    float acc[4][4] = {};

    for (int kb = 0; kb < K; kb += 16) {
        const float4 av = *(const float4*)(Ap + kb);
        const float4 bv = *(const float4*)(Bp + kb);
        __syncthreads();                       // prev-iter LDS reads complete
        As[lk+0][lr] = av.x; As[lk+1][lr] = av.y;
        As[lk+2][lr] = av.z; As[lk+3][lr] = av.w;
        Bs[lk+0][lr] = bv.x; Bs[lk+1][lr] = bv.y;
        Bs[lk+2][lr] = bv.z; Bs[lk+3][lr] = bv.w;
        __syncthreads();
        #pragma unroll
        for (int k = 0; k < 16; ++k) {
            const float4 a4 = *(const float4*)&As[k][ty << 2];
            const float ar[4] = {a4.x, a4.y, a4.z, a4.w};
            float br[4];
            #pragma unroll
            for (int j = 0; j < 4; ++j) br[j] = Bs[k][(tx << 2) + j];
            #pragma unroll
            for (int i = 0; i < 4; ++i)
                #pragma unroll
                for (int j = 0; j < 4; ++j)
                    acc[i][j] = fmaf(ar[i], br[j], acc[i][j]);
        }
    }

    #pragma unroll
    for (int i = 0; i < 4; ++i) {
        const int r = rowbase + (ty << 2) + i;
        const int c = colbase + (tx << 2);
        float4 o;
        o.x = acc[i][0]; o.y = acc[i][1]; o.z = acc[i][2]; o.w = acc[i][3];
        if (BIAS) {
            o.x += bias[c + 0]; o.y += bias[c + 1];
            o.z += bias[c + 2]; o.w += bias[c + 3];
        }
        *(float4*)&C[(size_t)r * N + c] = o;
    }
}

// ---------------------------------------------------------------------------
// Flash attention, fp32. One block = one (b, h, 64-query-row tile).
// qkv layout: [B*N][2304], col = h*192 + s*64 + d  (s = 0:q 1:k 2:v).
// Writes attn_out[b*N + n][h*64 + d]  (i.e. already back in [B,N,C]).
// LDS: Qs(17.0KB, stride 68 so f4 reads are 16B-aligned & conflict-free)
//      KP (16.6KB, stride 65) -- K during QK^T, then reused for P (lifetimes
//      disjoint), Vt(16.6KB, V transposed [d][key]).  Total 50.7KB -> 3 blk/CU.
// ---------------------------------------------------------------------------
__global__ __launch_bounds__(256)
void attn_kernel(const float* __restrict__ qkv, float* __restrict__ out) {
    __shared__ float Qs[64][68];
    __shared__ float KP[64][65];
    __shared__ float Vt[64][65];

    const int tid = threadIdx.x;
    const int tx  = tid & 15;
    const int ty  = tid >> 4;
    const int bh  = blockIdx.y;
    const int b   = bh / NHEADS;
    const int h   = bh % NHEADS;
    const int q0  = blockIdx.x << 6;

    const size_t headbase = (size_t)b * SEQ * QKVD + (size_t)h * 192;

    const int lr = tid >> 2;          // 0..63
    const int lc = (tid & 3) << 4;    // 0,16,32,48

    // stage Q once
    {
        const float* src = qkv + headbase + (size_t)(q0 + lr) * QKVD + lc;
        #pragma unroll
        for (int q = 0; q < 4; ++q) {
            const float4 v = *(const float4*)(src + (q << 2));
            *(float4*)&Qs[lr][lc + (q << 2)] = v;
        }
    }

    float o[4][4] = {};
    float mrow[4] = {-INFINITY, -INFINITY, -INFINITY, -INFINITY};
    float lrow[4] = {0.f, 0.f, 0.f, 0.f};
    const float scale = 0.125f;   // hd^-0.5

    for (int kb = 0; kb < SEQ; kb += 64) {
        // issue K/V global loads into registers (overlaps prev-iter compute)
        const float* ksrc = qkv + headbase + (size_t)(kb + lr) * QKVD + HD     + lc;
        const float* vsrc = qkv + headbase + (size_t)(kb + lr) * QKVD + 2 * HD + lc;
        float4 kvv[4], vvv[4];
        #pragma unroll
        for (int q = 0; q < 4; ++q) {
            kvv[q] = *(const float4*)(ksrc + (q << 2));
            vvv[q] = *(const float4*)(vsrc + (q << 2));
        }
        __syncthreads();   // prev-iter PV reads (KP/Vt) + Q staging done
        #pragma unroll
        for (int q = 0; q < 4; ++q) {
            const int c = lc + (q << 2);
            KP[lr][c+0] = kvv[q].x; KP[lr][c+1] = kvv[q].y;
            KP[lr][c+2] = kvv[q].z; KP[lr][c+3] = kvv[q].w;
            Vt[c+0][lr] = vvv[q].x; Vt[c+1][lr] = vvv[q].y;
            Vt[c+2][lr] = vvv[q].z; Vt[c+3][lr] = vvv[q].w;
        }
        __syncthreads();

        // S = Q K^T  (s[i][j]: row = ty*4+i, key = tx*4+j)
        float s[4][4] = {};
        #pragma unroll
        for (int d4 = 0; d4 < 16; ++d4) {
            float4 qa[4];
            #pragma unroll
            for (int i = 0; i < 4; ++i)
                qa[i] = *(const float4*)&Qs[(ty << 2) + i][d4 << 2];
            const float qr[4][4] = {
                {qa[0].x, qa[0].y, qa[0].z, qa[0].w},
                {qa[1].x, qa[1].y, qa[1].z, qa[1].w},
                {qa[2].x, qa[2].y, qa[2].z, qa[2].w},
                {qa[3].x, qa[3].y, qa[3].z, qa[3].w}};
            #pragma unroll
            for (int q = 0; q < 4; ++q) {
                const int d = (d4 << 2) + q;
                float kr[4];
                #pragma unroll
                for (int j = 0; j < 4; ++j) kr[j] = KP[(tx << 2) + j][d];
                #pragma unroll
                for (int i = 0; i < 4; ++i)
                    #pragma unroll
                    for (int j = 0; j < 4; ++j)
                        s[i][j] = fmaf(qr[i][q], kr[j], s[i][j]);
            }
        }

        // online softmax (row stats replicated across the 16 tx lanes)
        float alpha[4];
        #pragma unroll
        for (int i = 0; i < 4; ++i) {
            #pragma unroll
            for (int j = 0; j < 4; ++j) s[i][j] *= scale;
            float rm = fmaxf(fmaxf(s[i][0], s[i][1]), fmaxf(s[i][2], s[i][3]));
            #pragma unroll
            for (int off = 1; off < 16; off <<= 1)
                rm = fmaxf(rm, __shfl_xor(rm, off, 64));
            const float mn = fmaxf(mrow[i], rm);
            alpha[i] = __expf(mrow[i] - mn);
            mrow[i] = mn;
            float ps = 0.f;
            #pragma unroll
            for (int j = 0; j < 4; ++j) {
                const float p = __expf(s[i][j] - mn);
                s[i][j] = p;
                ps += p;
            }
            #pragma unroll
            for (int off = 1; off < 16; off <<= 1)
                ps += __shfl_xor(ps, off, 64);
            lrow[i] = lrow[i] * alpha[i] + ps;
            #pragma unroll
            for (int j = 0; j < 4; ++j) o[i][j] *= alpha[i];
        }

        __syncthreads();   // all K reads done before P overwrites KP
        #pragma unroll
        for (int i = 0; i < 4; ++i)
            #pragma unroll
            for (int j = 0; j < 4; ++j)
                KP[(ty << 2) + i][(tx << 2) + j] = s[i][j];
        __syncthreads();

        // O += P @ V   (reads P rows broadcast over tx; Vt cols 2-way free)
        #pragma unroll 4
        for (int k = 0; k < 64; ++k) {
            float pr[4], vr[4];
            #pragma unroll
            for (int i = 0; i < 4; ++i) pr[i] = KP[(ty << 2) + i][k];
            #pragma unroll
            for (int j = 0; j < 4; ++j) vr[j] = Vt[(tx << 2) + j][k];
            #pragma unroll
            for (int i = 0; i < 4; ++i)
                #pragma unroll
                for (int j = 0; j < 4; ++j)
                    o[i][j] = fmaf(pr[i], vr[j], o[i][j]);
        }
    }

    #pragma unroll
    for (int i = 0; i < 4; ++i) {
        const float inv = 1.f / lrow[i];
        float4 res;
        res.x = o[i][0] * inv; res.y = o[i][1] * inv;
        res.z = o[i][2] * inv; res.w = o[i][3] * inv;
        const size_t row = (size_t)b * SEQ + q0 + (ty << 2) + i;
        *(float4*)&out[row * CD + (size_t)h * HD + (tx << 2)] = res;
    }
}

// ---------------------------------------------------------------------------
extern "C" void kernel_launch(void* const* d_in, const int* in_sizes, int n_in,
                              void* d_out, int out_size, void* d_ws, size_t ws_size,
                              hipStream_t stream) {
    const float* x     = (const float*)d_in[0];   // [2,2048,768]
    const float* w_qkv = (const float*)d_in[1];   // [2304,768]
    const float* w_mlp = (const float*)d_in[2];   // [768,768]
    const float* b_mlp = (const float*)d_in[3];   // [768]
    float* out = (float*)d_out;                   // [2,2048,768] fp32

    // workspace: qkv (B*N*2304 f32 = 37.7MB) + attn_out (B*N*768 f32 = 12.6MB)
    float* qkv  = (float*)d_ws;
    float* attn = qkv + (size_t)BB * SEQ * QKVD;

    const int M = BB * SEQ;   // 4096

    // 1) qkv = x @ w_qkv^T
    {
        dim3 grid(QKVD / 64, M / 64);
        gemm_nt_kernel<false><<<grid, 256, 0, stream>>>(x, w_qkv, nullptr, qkv,
                                                        M, QKVD, CD);
    }
    // 2) flash attention per (b, h, q-tile)
    {
        dim3 grid(SEQ / 64, BB * NHEADS);
        attn_kernel<<<grid, 256, 0, stream>>>(qkv, attn);
    }
    // 3) out = attn @ w_mlp^T + b_mlp
    {
        dim3 grid(CD / 64, M / 64);
        gemm_nt_kernel<true><<<grid, 256, 0, stream>>>(attn, w_mlp, b_mlp, out,
                                                       M, CD, CD);
    }
}

// Round 2
// 126.595 us; speedup vs baseline: 6.6282x; 6.6282x over previous
//
#include <hip/hip_runtime.h>
#include <math.h>

typedef unsigned short u16;
typedef __attribute__((ext_vector_type(8))) short s8v;   // 8 bf16 (4 VGPRs)
typedef __attribute__((ext_vector_type(4))) short s4v;   // 4 bf16
typedef __attribute__((ext_vector_type(4))) float f4v;   // MFMA C/D

#define NHEADS 12
#define SEQ 2048
#define CD 768
#define BB 2
#define QKVD 2304

__device__ inline u16 f2bf(float f) {            // RNE fp32->bf16
    union { float f; unsigned u; } v; v.f = f;
    unsigned r = v.u + 0x7FFFu + ((v.u >> 16) & 1u);
    return (u16)(r >> 16);
}

// async global->LDS, 16B per lane; DST must be wave-uniform (lane*16 added by HW)
#define GLOAD16(SRC, DST) __builtin_amdgcn_global_load_lds(                 \
    (const __attribute__((address_space(1))) void*)(SRC),                   \
    (__attribute__((address_space(3))) void*)(DST), 16, 0, 0)

// XOR swizzle for row-major [R][64] bf16 tiles (128B rows): ushort index
#define SW(r, c) ((((r) << 6) + (c)) ^ (((r) & 7) << 3))

// ---------------------------------------------------------------------------
__global__ __launch_bounds__(256)
void cvt_kernel(const float* __restrict__ in, u16* __restrict__ out, int n) {
    const int i = (blockIdx.x * 256 + threadIdx.x) * 8;
    if (i >= n) return;
    const float4 a = *(const float4*)(in + i);
    const float4 b = *(const float4*)(in + i + 4);
    s8v o;
    o[0] = (short)f2bf(a.x); o[1] = (short)f2bf(a.y);
    o[2] = (short)f2bf(a.z); o[3] = (short)f2bf(a.w);
    o[4] = (short)f2bf(b.x); o[5] = (short)f2bf(b.y);
    o[6] = (short)f2bf(b.z); o[7] = (short)f2bf(b.w);
    *(s8v*)(out + i) = o;
}

// ---------------------------------------------------------------------------
// C = A @ W^T (+bias). A[M][K], W[N][K] bf16, K%64==0, M%128==0, N%128==0.
// 128x128 tile, BK=64, 256 thr (4 waves, 2x2), 16x16x32 MFMA, m97 structure.
// ---------------------------------------------------------------------------
template<bool OUT_BF16, bool BIAS>
__global__ __launch_bounds__(256)
void gemm_bf16(const u16* __restrict__ A, const u16* __restrict__ W,
               const float* __restrict__ bias, void* __restrict__ Cout,
               int M, int N, int K) {
    __shared__ u16 As[8192];   // [128][64] swizzled
    __shared__ u16 Bs[8192];
    const int tid = threadIdx.x;
    const int l  = tid & 63, w = tid >> 6;
    const int wr = w >> 1, wc = w & 1;
    const int lq = l & 15, lg = l >> 4;
    const int rowBase = blockIdx.y << 7, colBase = blockIdx.x << 7;

    f4v acc[4][4];
    #pragma unroll
    for (int m = 0; m < 4; ++m)
        #pragma unroll
        for (int n = 0; n < 4; ++n)
            #pragma unroll
            for (int r = 0; r < 4; ++r) acc[m][n][r] = 0.f;

    const int chunk = l & 7;      // 16B chunk within a 128B row
    const int r8    = l >> 3;     // row within an 8-row group

    for (int kb = 0; kb < K; kb += 64) {
        __syncthreads();          // previous iter's ds_reads complete
        #pragma unroll
        for (int j = 0; j < 4; ++j) {
            const int rowA = (w << 5) + (j << 3) + r8;   // 0..127
            const int sc   = (chunk ^ (rowA & 7)) << 3;  // pre-swizzled source
            GLOAD16(A + (size_t)(rowBase + rowA) * K + kb + sc,
                    &As[(w << 11) + (j << 9)]);
            GLOAD16(W + (size_t)(colBase + rowA) * K + kb + sc,
                    &Bs[(w << 11) + (j << 9)]);
        }
        __syncthreads();          // vmcnt(0) drained before barrier -> visible
        #pragma unroll
        for (int h = 0; h < 2; ++h) {
            const int kc = (h << 5) + (lg << 3);
            s8v af[4], bf[4];
            #pragma unroll
            for (int m = 0; m < 4; ++m) {
                af[m] = *(const s8v*)&As[SW((wr << 6) + (m << 4) + lq, kc)];
                bf[m] = *(const s8v*)&Bs[SW((wc << 6) + (m << 4) + lq, kc)];
            }
            #pragma unroll
            for (int m = 0; m < 4; ++m)
                #pragma unroll
                for (int n = 0; n < 4; ++n)
                    acc[m][n] = __builtin_amdgcn_mfma_f32_16x16x32_bf16(
                        af[m], bf[n], acc[m][n], 0, 0, 0);
        }
    }

    // epilogue: D layout col=l&15, row=(l>>4)*4+reg
    #pragma unroll
    for (int m = 0; m < 4; ++m)
        #pragma unroll
        for (int r = 0; r < 4; ++r) {
            const int row = rowBase + (wr << 6) + (m << 4) + (lg << 2) + r;
            #pragma unroll
            for (int n = 0; n < 4; ++n) {
                const int col = colBase + (wc << 6) + (n << 4) + lq;
                float v = acc[m][n][r];
                if (BIAS) v += bias[col];
                if (OUT_BF16) ((u16*)Cout)[(size_t)row * N + col] = f2bf(v);
                else        ((float*)Cout)[(size_t)row * N + col] = v;
            }
        }
}

// ---------------------------------------------------------------------------
// MFMA flash attention. Block = (b,h, 64 q-rows), 4 waves x 16 q-rows.
// qkv bf16 [B*N][2304], col = h*192 + {0,64,128} + d. Out bf16 [B*N][768].
// Swapped QK^T: S^T = mfma(K, Q) -> lane owns q = l&15, keys (l>>4)*4+r+16kb.
// P bounced via QP LDS (Q region reused). V staged transposed.
// ---------------------------------------------------------------------------
__global__ __launch_bounds__(256)
void attn_mfma(const u16* __restrict__ qkv, u16* __restrict__ outb) {
    __shared__ u16 Klds[4096];   // [key][d] swz
    __shared__ u16 Vt[4096];     // [d][key] swz
    __shared__ u16 QP[4096];     // [qrow][d] swz; later P [qrow][key]
    const int tid = threadIdx.x;
    const int l = tid & 63, w = tid >> 6;
    const int lq = l & 15, lg = l >> 4;
    const int q0 = blockIdx.x << 6;
    const int bh = blockIdx.y;
    const int b = bh / NHEADS, h = bh % NHEADS;
    const u16* base = qkv + (size_t)b * SEQ * QKVD + h * 192;

    {   // stage Q: thread covers qrow=l, chunks {w, w+4}
        const u16* qsrc = base + (size_t)(q0 + l) * QKVD;
        const s8v q1 = *(const s8v*)(qsrc + (w << 3));
        const s8v q2 = *(const s8v*)(qsrc + ((w + 4) << 3));
        *(s8v*)&QP[SW(l, (w << 3))] = q1;
        *(s8v*)&QP[SW(l, ((w + 4) << 3))] = q2;
    }
    __syncthreads();
    s8v qf[2];                    // B-frag: col=q (lq), k=d=lg*8+r (+32h)
    #pragma unroll
    for (int h2 = 0; h2 < 2; ++h2)
        qf[h2] = *(const s8v*)&QP[SW((w << 4) + lq, (h2 << 5) + (lg << 3))];

    f4v oacc[4];
    #pragma unroll
    for (int db = 0; db < 4; ++db)
        #pragma unroll
        for (int r = 0; r < 4; ++r) oacc[db][r] = 0.f;
    float mrun = -INFINITY, lrun = 0.f;

    for (int t = 0; t < 32; ++t) {
        // K/V tile global loads into regs (issued before barrier: overlap)
        const u16* ksrc = base + (size_t)(t * 64 + l) * QKVD + 64;
        const s8v kr0 = *(const s8v*)(ksrc + (w << 3));
        const s8v kr1 = *(const s8v*)(ksrc + ((w + 4) << 3));
        const s8v vr0 = *(const s8v*)(ksrc + 64 + (w << 3));
        const s8v vr1 = *(const s8v*)(ksrc + 64 + ((w + 4) << 3));
        __syncthreads();          // prev tile's LDS reads done
        *(s8v*)&Klds[SW(l, (w << 3))] = kr0;
        *(s8v*)&Klds[SW(l, ((w + 4) << 3))] = kr1;
        #pragma unroll
        for (int e = 0; e < 8; ++e) {   // transpose V: fixed d per instr -> free
            Vt[SW((w << 3) + e, l)]       = (u16)vr0[e];
            Vt[SW(((w + 4) << 3) + e, l)] = (u16)vr1[e];
        }
        __syncthreads();

        // S^T = K Q^T: D[key][q], lane: q=lq, key=kb*16+lg*4+r
        f4v sa[4];
        #pragma unroll
        for (int kb = 0; kb < 4; ++kb) {
            const s8v k0 = *(const s8v*)&Klds[SW((kb << 4) + lq, (lg << 3))];
            const s8v k1 = *(const s8v*)&Klds[SW((kb << 4) + lq, 32 + (lg << 3))];
            f4v z;
            #pragma unroll
            for (int r = 0; r < 4; ++r) z[r] = 0.f;
            z = __builtin_amdgcn_mfma_f32_16x16x32_bf16(k0, qf[0], z, 0, 0, 0);
            sa[kb] = __builtin_amdgcn_mfma_f32_16x16x32_bf16(k1, qf[1], z, 0, 0, 0);
        }

        // online softmax for q=lq (16 keys/lane, reduce over lanes l^16,l^32)
        float p[16];
        float mx = -INFINITY;
        #pragma unroll
        for (int kb = 0; kb < 4; ++kb)
            #pragma unroll
            for (int r = 0; r < 4; ++r) {
                const float sv = sa[kb][r] * 0.125f;
                p[kb * 4 + r] = sv;
                mx = fmaxf(mx, sv);
            }
        mx = fmaxf(mx, __shfl_xor(mx, 16));
        mx = fmaxf(mx, __shfl_xor(mx, 32));
        const float mn = fmaxf(mrun, mx);
        const float al = __expf(mrun - mn);
        mrun = mn;
        float sum = 0.f;
        #pragma unroll
        for (int i = 0; i < 16; ++i) {
            p[i] = __expf(p[i] - mn);
            sum += p[i];
        }
        sum += __shfl_xor(sum, 16);
        sum += __shfl_xor(sum, 32);
        lrun = lrun * al + sum;

        // rescale O (O lane-ownership: q' = lg*4+r) via 4 shuffles
        float ar[4];
        #pragma unroll
        for (int r = 0; r < 4; ++r) ar[r] = __shfl(al, (lg << 2) + r);
        #pragma unroll
        for (int db = 0; db < 4; ++db)
            #pragma unroll
            for (int r = 0; r < 4; ++r) oacc[db][r] *= ar[r];

        // write P (bf16) to wave-private QP rows [w*16, w*16+16)
        #pragma unroll
        for (int kb = 0; kb < 4; ++kb) {
            s4v pw;
            #pragma unroll
            for (int r = 0; r < 4; ++r) pw[r] = (short)f2bf(p[kb * 4 + r]);
            *(s4v*)&QP[SW((w << 4) + lq, (kb << 4) + (lg << 2))] = pw;
        }
        // PV: A=P (row=q=lq, k=key), B=Vt (col=d=lq, k=key)
        const s8v pf0 = *(const s8v*)&QP[SW((w << 4) + lq, (lg << 3))];
        const s8v pf1 = *(const s8v*)&QP[SW((w << 4) + lq, 32 + (lg << 3))];
        #pragma unroll
        for (int db = 0; db < 4; ++db) {
            const s8v v0 = *(const s8v*)&Vt[SW((db << 4) + lq, (lg << 3))];
            const s8v v1 = *(const s8v*)&Vt[SW((db << 4) + lq, 32 + (lg << 3))];
            oacc[db] = __builtin_amdgcn_mfma_f32_16x16x32_bf16(pf0, v0, oacc[db], 0, 0, 0);
            oacc[db] = __builtin_amdgcn_mfma_f32_16x16x32_bf16(pf1, v1, oacc[db], 0, 0, 0);
        }
    }

    // epilogue: O[q'][d], q' = lg*4+r, d = db*16+lq
    #pragma unroll
    for (int r = 0; r < 4; ++r) {
        const float li = __shfl(lrun, (lg << 2) + r);
        const float inv = 1.f / li;
        const size_t row = (size_t)b * SEQ + q0 + (w << 4) + (lg << 2) + r;
        #pragma unroll
        for (int db = 0; db < 4; ++db)
            outb[row * CD + h * 64 + (db << 4) + lq] = f2bf(oacc[db][r] * inv);
    }
}

// ---------------------------------------------------------------------------
extern "C" void kernel_launch(void* const* d_in, const int* in_sizes, int n_in,
                              void* d_out, int out_size, void* d_ws, size_t ws_size,
                              hipStream_t stream) {
    const float* x     = (const float*)d_in[0];
    const float* w_qkv = (const float*)d_in[1];
    const float* w_mlp = (const float*)d_in[2];
    const float* b_mlp = (const float*)d_in[3];
    float* out = (float*)d_out;

    const int NX  = BB * SEQ * CD;        // 3,145,728
    const int NWQ = QKVD * CD;            // 1,769,472
    const int NWM = CD * CD;              //   589,824
    const int NQK = BB * SEQ * QKVD;      // 9,437,184

    u16* xb    = (u16*)d_ws;
    u16* wqkvb = xb + NX;
    u16* wmlpb = wqkvb + NWQ;
    u16* qkvb  = wmlpb + NWM;
    u16* attnb = qkvb + NQK;

    cvt_kernel<<<NX  / 2048, 256, 0, stream>>>(x,     xb,    NX);
    cvt_kernel<<<NWQ / 2048, 256, 0, stream>>>(w_qkv, wqkvb, NWQ);
    cvt_kernel<<<NWM / 2048, 256, 0, stream>>>(w_mlp, wmlpb, NWM);

    const int M = BB * SEQ;   // 4096
    {   // qkv = x @ w_qkv^T  -> bf16
        dim3 grid(QKVD / 128, M / 128);
        gemm_bf16<true, false><<<grid, 256, 0, stream>>>(xb, wqkvb, nullptr,
                                                         qkvb, M, QKVD, CD);
    }
    {   // attention
        dim3 grid(SEQ / 64, BB * NHEADS);
        attn_mfma<<<grid, 256, 0, stream>>>(qkvb, attnb);
    }
    {   // out = attn @ w_mlp^T + b  -> fp32
        dim3 grid(CD / 128, M / 128);
        gemm_bf16<false, true><<<grid, 256, 0, stream>>>(attnb, wmlpb, b_mlp,
                                                         out, M, CD, CD);
    }
}